// Round 2
// baseline (678.981 us; speedup 1.0000x reference)
//
#include <hip/hip_runtime.h>
#include <hip/hip_bf16.h>
#include <math.h>

#define D     128
#define NHEAD 4
#define DH    32
#define DFF   512
#define DIN   16
#define MAXDEG 64
#define TN    16

typedef __attribute__((ext_vector_type(8))) short bf16x8;
typedef __attribute__((ext_vector_type(4))) float f32x4;
typedef __hip_bfloat16 bf16;

// 1/sqrt(32) * log2(e): q pre-scaled so attn weight = exp2(q.k)
#define QSCALE_L2E 0.2550348838f

// r9/r11: pad-132 LDS was for scalar-write conflict avoidance (superseded).
// r10: register-prefetch of weight tiles spills — don't (superseded by
//      global_load_lds: no data VGPRs).
// r13: A-fragments in 16 VGPRs straight from global; best dense config.
// r14: wo+ffn mega-fusion REGRESSED — dense chain is latency-plateau'd.
// r16: dispatch/traffic elimination outside inner loops works (+22 µs).
// r18: dense kernels rebuilt on global_load_lds + raw s_barrier + counted
//      vmcnt + XOR-swizzled linear LDS. 728->641 µs; k_ffn left top-5.
// r19 (this round): k_attn is top kernel (4x48 µs), latency-bound
//      (HBM 40%, VALU 54%, occ 63%). Fix the latency chain: (a) whole CSR
//      row preloaded in ONE coalesced load + __shfl index broadcast
//      (removes load->gather dependency hop); (b) 16 edges in flight
//      (2 slots x 8-deep): 90% of waves (deg<=16) finish in one gather
//      round instead of two. VGPR 32->~60, still 8 waves/SIMD tier.
#define BM 64

#define WAITV(N) asm volatile("s_waitcnt vmcnt(" #N ")" ::: "memory")
#define WAITLGKM asm volatile("s_waitcnt lgkmcnt(0)" ::: "memory")
#define FENCE()  asm volatile("" ::: "memory")
#define BAR() do { FENCE(); __builtin_amdgcn_s_barrier(); FENCE(); } while (0)

__device__ __forceinline__ void gll16(const bf16* g, bf16* l) {
    __builtin_amdgcn_global_load_lds((__attribute__((address_space(1))) void*)g,
                                     (__attribute__((address_space(3))) void*)l,
                                     16, 0, 0);
}

__device__ __forceinline__ ushort bfbits(float f) {
    __hip_bfloat16 b = __float2bfloat16(f);
    return *(ushort*)&b;
}

// ---------------- CSR fill (deg zeroed by k_wt region 25) ----------------
__global__ void k_fill(const int* __restrict__ recv, const int* __restrict__ senders,
                       int* __restrict__ deg, int* __restrict__ eid, int E) {
    int e = blockIdx.x * blockDim.x + threadIdx.x;
    if (e >= E) return;
    int r = recv[e];
    int pos = atomicAdd(&deg[r], 1);
    if (pos < MAXDEG) eid[r * MAXDEG + pos] = senders[e];
}

// ---------------- weight transpose + bf16 convert + deg zero (26 regions) ----
__global__ void k_wt(const float* __restrict__ wq, const float* __restrict__ wk,
                     const float* __restrict__ wv, const float* __restrict__ wo,
                     const float* __restrict__ w1, const float* __restrict__ w2,
                     const float* __restrict__ encw2,
                     bf16* __restrict__ wqkvT, bf16* __restrict__ woT,
                     bf16* __restrict__ w1T, bf16* __restrict__ w2T,
                     bf16* __restrict__ encw2T, int* __restrict__ deg, int N) {
    int r = blockIdx.y;
    if (r == 25) {                       // zero deg (runs before k_fill)
        int i = blockIdx.x * blockDim.x + threadIdx.x;
        if (i < N) deg[i] = 0;
        return;
    }
    const float* src; bf16* dst; int K, Nout;
    if (r < 12) {
        int l = r / 3, sel = r % 3;
        src = (sel == 0 ? wq : sel == 1 ? wk : wv) + (size_t)l * D * D;
        dst = wqkvT + (size_t)l * 3 * D * D + (size_t)sel * D * D;
        K = D; Nout = D;
    } else if (r < 16) {
        int l = r - 12;
        src = wo + (size_t)l * D * D; dst = woT + (size_t)l * D * D; K = D; Nout = D;
    } else if (r < 20) {
        int l = r - 16;
        src = w1 + (size_t)l * D * DFF; dst = w1T + (size_t)l * D * DFF; K = D; Nout = DFF;
    } else if (r < 24) {
        int l = r - 20;
        src = w2 + (size_t)l * DFF * D; dst = w2T + (size_t)l * DFF * D; K = DFF; Nout = D;
    } else {
        src = encw2; dst = encw2T; K = D; Nout = D;
    }
    int total = K * Nout;
    int i = blockIdx.x * blockDim.x + threadIdx.x;
    if (i >= total) return;
    int k = i / Nout, j = i % Nout;
    dst[(size_t)j * K + k] = __float2bfloat16(src[i]);
}

// helper: load this wave's 4 A-fragments (16 rows x 128 cols) from global
__device__ __forceinline__ void load_afrag(const bf16* A, int arow, int quad,
                                           int N, bf16x8* afr) {
    const bf16* ab = A + (size_t)arow * D + quad * 8;
#pragma unroll
    for (int i = 0; i < 4; i++) {
        uint4 v = make_uint4(0u, 0u, 0u, 0u);
        if (arow < N) v = *(const uint4*)(ab + i * 32);
        afr[i] = *(bf16x8*)&v;
    }
}

// ---- stage a full 128x128 weight tile (32KB) via global_load_lds ----------
// LDS linear [128][128]; granule(16B) swizzle: LDS (r,gL) <- src (r, gL^(r&15))
__device__ __forceinline__ void stage_full(bf16* lb, const bf16* src,
                                           int wave, int lane) {
#pragma unroll
    for (int k = 0; k < 8; k++) {
        int gidx = (wave * 8 + k) * 64 + lane;
        int r = gidx >> 4, gL = gidx & 15;
        gll16(src + (size_t)r * 128 + ((gL ^ (r & 15)) * 8),
              lb + (size_t)(wave * 8 + k) * 512);
    }
}

// ---- stage a 128x64 half-tile (16KB): LDS [128][64], mask 7 ---------------
__device__ __forceinline__ void stage_half(bf16* lb, const bf16* src, int rs,
                                           int wave, int lane) {
#pragma unroll
    for (int k = 0; k < 4; k++) {
        int gidx = (wave * 4 + k) * 64 + lane;
        int r = gidx >> 3, gL = gidx & 7;
        gll16(src + (size_t)r * rs + ((gL ^ (r & 7)) * 8),
              lb + (size_t)(wave * 4 + k) * 512);
    }
}

// MFMA over a full swizzled tile: acc[j] += A(afr) * W[128][128]
__device__ __forceinline__ void mfma_tile(const bf16* Wb, const bf16x8* afr,
                                          f32x4* acc, int l16, int quad) {
#pragma unroll
    for (int i = 0; i < 4; i++)
#pragma unroll
        for (int j = 0; j < 8; j++) {
            const bf16* wp = Wb + (size_t)(j * 16 + l16) * 128
                              + (size_t)((((i * 4 + quad)) ^ l16) * 8);
            acc[j] = __builtin_amdgcn_mfma_f32_16x16x32_bf16(afr[i], *(const bf16x8*)wp,
                                                             acc[j], 0, 0, 0);
        }
}

// ---------------- bf16 MFMA GEMM, 64 rows x 128 cols, K=128 ----------------
// OPs: 2 RES_LN (wo+ln2), 5 BIAS_LN (encode+ln1_0)
template<int OP>
__global__ __launch_bounds__(256) void k_gemm(
        const bf16* __restrict__ A, const bf16* __restrict__ Bt,
        const float* __restrict__ bias,
        const float* __restrict__ lns, const float* __restrict__ lnb,
        float* x, bf16* outB, int N) {
    __shared__ alignas(16) bf16 Wsm[128 * 128];   // 32 KB -> 4-5 blocks/CU
    int m0 = blockIdx.x * BM;
    int t = threadIdx.x;
    int wave = t >> 6, lane = t & 63;
    int quad = lane >> 4, l16 = lane & 15;
    int wm = wave * 16;

    bf16x8 afr[4];
    load_afrag(A, m0 + wm + l16, quad, N, afr);
    FENCE();
    stage_full(Wsm, Bt, wave, lane);
    WAITV(0); BAR();

    int rowb = m0 + wm + quad * 4;
    float xv[8][4];
    if (OP == 2) {   // hoist residual reads: latency hides under MFMA phase
#pragma unroll
        for (int j = 0; j < 8; j++)
#pragma unroll
            for (int r = 0; r < 4; r++) {
                int gr = rowb + r;
                xv[j][r] = (gr < N) ? x[(size_t)gr * D + j * 16 + l16] : 0.f;
            }
    }

    f32x4 acc[8];
#pragma unroll
    for (int j = 0; j < 8; j++) acc[j] = (f32x4){0.f, 0.f, 0.f, 0.f};
    mfma_tile(Wsm, afr, acc, l16, quad);

    float bv[8];
    if (OP == 5) {
#pragma unroll
        for (int j = 0; j < 8; j++) bv[j] = bias[j * 16 + l16];
    }
#pragma unroll
    for (int j = 0; j < 8; j++) {
#pragma unroll
        for (int r = 0; r < 4; r++) {
            int gr = rowb + r;
            if (gr >= N) continue;
            float val = acc[j][r];
            if (OP == 5) val += bv[j];
            if (OP == 2) val += xv[j][r];
            acc[j][r] = val;
        }
    }
    float lsv[8], lbv[8];
#pragma unroll
    for (int j = 0; j < 8; j++) {
        lsv[j] = lns[j * 16 + l16];
        lbv[j] = lnb[j * 16 + l16];
    }
#pragma unroll
    for (int r = 0; r < 4; r++) {
        float s1 = 0.f, s2 = 0.f;
#pragma unroll
        for (int j = 0; j < 8; j++) {
            float v = acc[j][r];
            s1 += v; s2 += v * v;
        }
        s1 += __shfl_xor(s1, 1, 64);  s2 += __shfl_xor(s2, 1, 64);
        s1 += __shfl_xor(s1, 2, 64);  s2 += __shfl_xor(s2, 2, 64);
        s1 += __shfl_xor(s1, 4, 64);  s2 += __shfl_xor(s2, 4, 64);
        s1 += __shfl_xor(s1, 8, 64);  s2 += __shfl_xor(s2, 8, 64);
        float mu = s1 * (1.f / 128.f);
        float var = s2 * (1.f / 128.f) - mu * mu;
        float rinv = rsqrtf(fmaxf(var, 0.f) + 1e-5f);
        int gr = rowb + r;
        if (gr >= N) continue;
#pragma unroll
        for (int j = 0; j < 8; j++) {
            int col = j * 16 + l16;
            float v = acc[j][r];
            x[(size_t)gr * D + col] = v;
            outB[(size_t)gr * D + col] =
                __float2bfloat16((v - mu) * rinv * lsv[j] + lbv[j]);
        }
    }
}

// ---------------- fused QKV: double-buffered gll pipeline -------------------
// Outputs kept in regs; stored once at the end so stores never enter the
// vmcnt counting of the pipeline.
__global__ __launch_bounds__(256) void k_qkv(
        const bf16* __restrict__ hb, const bf16* __restrict__ wqkvT,
        bf16* __restrict__ qb, bf16* __restrict__ kvb, int N) {
    __shared__ alignas(16) bf16 Wbuf[2][128 * 128];   // 64 KB -> 2 blocks/CU
    int m0 = blockIdx.x * BM;
    int t = threadIdx.x;
    int wave = t >> 6, lane = t & 63;
    int quad = lane >> 4, l16 = lane & 15;
    int wm = wave * 16;

    bf16x8 afr[4];
    load_afrag(hb, m0 + wm + l16, quad, N, afr);
    FENCE();
    stage_full(Wbuf[0], wqkvT, wave, lane);               // q tile
    FENCE();
    stage_full(Wbuf[1], wqkvT + (size_t)D * D, wave, lane); // k tile
    FENCE();

    f32x4 aq[8], ak[8], av[8];
#pragma unroll
    for (int j = 0; j < 8; j++) aq[j] = (f32x4){0.f, 0.f, 0.f, 0.f};

    WAITV(8); BAR();                 // q tile (+afr) ready; k tile in flight
    __builtin_amdgcn_s_setprio(1);
    mfma_tile(Wbuf[0], afr, aq, l16, quad);
    __builtin_amdgcn_s_setprio(0);
    BAR();                           // buf0 free
    stage_full(Wbuf[0], wqkvT + (size_t)2 * D * D, wave, lane);  // v tile
    FENCE();
    WAITV(8); BAR();                 // k tile ready; v tile in flight
#pragma unroll
    for (int j = 0; j < 8; j++) ak[j] = (f32x4){0.f, 0.f, 0.f, 0.f};
    __builtin_amdgcn_s_setprio(1);
    mfma_tile(Wbuf[1], afr, ak, l16, quad);
    __builtin_amdgcn_s_setprio(0);
    WAITV(0); BAR();                 // v tile ready (issued 1.5 phases ago)
#pragma unroll
    for (int j = 0; j < 8; j++) av[j] = (f32x4){0.f, 0.f, 0.f, 0.f};
    __builtin_amdgcn_s_setprio(1);
    mfma_tile(Wbuf[0], afr, av, l16, quad);
    __builtin_amdgcn_s_setprio(0);

    int rowb = m0 + wm + quad * 4;
#pragma unroll
    for (int j = 0; j < 8; j++) {
        int col = j * 16 + l16;
#pragma unroll
        for (int r = 0; r < 4; r++) {
            int gr = rowb + r;
            if (gr >= N) continue;
            qb[(size_t)gr * D + col] = __float2bfloat16(aq[j][r] * QSCALE_L2E);
            uint kv = (uint)bfbits(ak[j][r]) | ((uint)bfbits(av[j][r]) << 16);
            *(uint*)&kvb[((size_t)gr * D + col) * 2] = kv;
        }
    }
}

// ---- stage FFN subtile ts (0..15): per c: {W1 h0, W1 h1, W2 h0, W2 h1} ----
__device__ __forceinline__ void stage_ffn_tile(int ts, const bf16* w1T,
                                               const bf16* w2T, bf16* Wb3,
                                               int wave, int lane) {
    int c = ts >> 2, ph = ts & 3;
    const bf16* src; int rs;
    if (ph < 2) { src = w1T + (size_t)(c * 128) * 128 + ph * 64; rs = 128; }
    else        { src = w2T + c * 128 + (ph - 2) * 64;           rs = DFF; }
    stage_half(Wb3 + (size_t)(ts % 3) * (64 * 128), src, rs, wave, lane);
}

// ---------------- fused FFN: 16-stage gll pipeline, ring of 3 subtiles ------
// x += relu(hb@w1+b1)@w2 + b2; then LN (MODE 0) or fused decode (MODE 1)
template<int MODE>
__global__ __launch_bounds__(256) void k_ffn(
        const bf16* __restrict__ hb, const bf16* __restrict__ w1T,
        const float* __restrict__ b1,
        const bf16* __restrict__ w2T, const float* __restrict__ b2,
        const float* __restrict__ lns, const float* __restrict__ lnb,
        const float* __restrict__ dw1, const float* __restrict__ db1,
        const float* __restrict__ dw2, const float* __restrict__ db2,
        float* x, bf16* outB, float* out, int N) {
    __shared__ alignas(16) bf16 Wb3[3][64 * 128];   // 48 KB ring
    __shared__ alignas(16) bf16 Hsm[64 * 128];      // 16 KB (swizzled) => 64 KB total
    int m0 = blockIdx.x * 64;
    int t = threadIdx.x;
    int wave = t >> 6, lane = t & 63;
    int quad = lane >> 4, l16 = lane & 15;
    int wm = wave * 16;
    int rowb = m0 + wm + quad * 4;

    // preload all b1 biases: keeps the pipeline free of stray vmem ops
    float b1pre[4][8];
#pragma unroll
    for (int c2 = 0; c2 < 4; c2++)
#pragma unroll
        for (int j = 0; j < 8; j++) b1pre[c2][j] = b1[c2 * 128 + j * 16 + l16];

    bf16x8 afr[4];
    load_afrag(hb, m0 + wm + l16, quad, N, afr);
    FENCE();
    stage_ffn_tile(0, w1T, w2T, &Wb3[0][0], wave, lane);
    FENCE();
    stage_ffn_tile(1, w1T, w2T, &Wb3[0][0], wave, lane);
    FENCE();

    f32x4 acc2[8], accP[8];
#pragma unroll
    for (int j = 0; j < 8; j++) acc2[j] = (f32x4){0.f, 0.f, 0.f, 0.f};
    float xv[8][4];

#pragma unroll
    for (int s = 0; s < 16; s++) {
        if (s < 15) { WAITV(4); } else { WAITV(0); }
        BAR();
        if (s + 2 < 16) {
            stage_ffn_tile(s + 2, w1T, w2T, &Wb3[0][0], wave, lane);
            FENCE();
        }
        const bf16* Wb = &Wb3[0][0] + (size_t)(s % 3) * (64 * 128);
        int c = s >> 2, ph = s & 3;
        if (s == 15) {   // residual prefetch: hides under last stage + epilogue
#pragma unroll
            for (int j = 0; j < 8; j++)
#pragma unroll
                for (int r = 0; r < 4; r++) {
                    int gr = rowb + r;
                    xv[j][r] = (gr < N) ? x[(size_t)gr * D + j * 16 + l16] : 0.f;
                }
        }
        if (ph < 2) {
            if (ph == 0) {
#pragma unroll
                for (int j = 0; j < 8; j++) accP[j] = (f32x4){0.f, 0.f, 0.f, 0.f};
            }
            __builtin_amdgcn_s_setprio(1);
#pragma unroll
            for (int i2 = 0; i2 < 2; i2++) {
#pragma unroll
                for (int j = 0; j < 8; j++) {
                    const bf16* wp = Wb + (size_t)(j * 16 + l16) * 64
                                      + (size_t)(((i2 * 4 + quad) ^ (l16 & 7)) * 8);
                    accP[j] = __builtin_amdgcn_mfma_f32_16x16x32_bf16(
                        afr[ph * 2 + i2], *(const bf16x8*)wp, accP[j], 0, 0, 0);
                }
            }
            __builtin_amdgcn_s_setprio(0);
            if (ph == 1) {   // relu+bias -> swizzled Hsm
                int rw = wm + quad * 4;
#pragma unroll
                for (int j = 0; j < 8; j++) {
                    int gb = j * 2 + (l16 >> 3), ce = l16 & 7;
#pragma unroll
                    for (int r = 0; r < 4; r++) {
                        int row = rw + r;
                        Hsm[(size_t)row * 128 + (size_t)((gb ^ (row & 15)) * 8) + ce] =
                            __float2bfloat16(fmaxf(accP[j][r] + b1pre[c][j], 0.f));
                    }
                }
                WAITLGKM;   // ds_writes visible to other waves at next barrier
            }
        } else {
            int h = ph - 2;
            __builtin_amdgcn_s_setprio(1);
#pragma unroll
            for (int k2 = 0; k2 < 2; k2++) {
                int ks = h * 2 + k2;
                const bf16* hp = Hsm + (size_t)(wm + l16) * 128
                                  + (size_t)(((ks * 4 + quad) ^ l16) * 8);
                bf16x8 af2 = *(const bf16x8*)hp;
#pragma unroll
                for (int j = 0; j < 8; j++) {
                    const bf16* wp = Wb + (size_t)(j * 16 + l16) * 64
                                      + (size_t)(((k2 * 4 + quad) ^ (l16 & 7)) * 8);
                    acc2[j] = __builtin_amdgcn_mfma_f32_16x16x32_bf16(
                        af2, *(const bf16x8*)wp, acc2[j], 0, 0, 0);
                }
            }
            __builtin_amdgcn_s_setprio(0);
        }
    }

    float bv[8];
#pragma unroll
    for (int j = 0; j < 8; j++) bv[j] = b2[j * 16 + l16];
#pragma unroll
    for (int j = 0; j < 8; j++) {
#pragma unroll
        for (int r = 0; r < 4; r++) {
            int gr = rowb + r;
            if (gr >= N) continue;
            acc2[j][r] += bv[j] + xv[j][r];
        }
    }
    if (MODE == 1) {
        float dw[8][3];
#pragma unroll
        for (int j = 0; j < 8; j++) {
            int col = j * 16 + l16;
#pragma unroll
            for (int cc3 = 0; cc3 < 3; cc3++) dw[j][cc3] = dw1[col * 3 + cc3];
        }
#pragma unroll
        for (int r = 0; r < 4; r++) {
            float s0 = 0.f, s1 = 0.f, s2 = 0.f;
#pragma unroll
            for (int j = 0; j < 8; j++) {
                float v = acc2[j][r];
                s0 += v * dw[j][0]; s1 += v * dw[j][1]; s2 += v * dw[j][2];
            }
            s0 += __shfl_xor(s0, 1, 64); s1 += __shfl_xor(s1, 1, 64); s2 += __shfl_xor(s2, 1, 64);
            s0 += __shfl_xor(s0, 2, 64); s1 += __shfl_xor(s1, 2, 64); s2 += __shfl_xor(s2, 2, 64);
            s0 += __shfl_xor(s0, 4, 64); s1 += __shfl_xor(s1, 4, 64); s2 += __shfl_xor(s2, 4, 64);
            s0 += __shfl_xor(s0, 8, 64); s1 += __shfl_xor(s1, 8, 64); s2 += __shfl_xor(s2, 8, 64);
            int gr = rowb + r;
            if (l16 == 0 && gr < N) {
                float t0 = fmaxf(s0 + db1[0], 0.f);
                float t1 = fmaxf(s1 + db1[1], 0.f);
                float t2 = fmaxf(s2 + db1[2], 0.f);
#pragma unroll
                for (int o = 0; o < 3; o++)
                    out[(size_t)gr * 3 + o] =
                        t0 * dw2[0 * 3 + o] + t1 * dw2[1 * 3 + o] + t2 * dw2[2 * 3 + o] + db2[o];
            }
        }
        return;
    }
    float lsv[8], lbv[8];
#pragma unroll
    for (int j = 0; j < 8; j++) {
        lsv[j] = lns[j * 16 + l16];
        lbv[j] = lnb[j * 16 + l16];
    }
#pragma unroll
    for (int r = 0; r < 4; r++) {
        float s1 = 0.f, s2 = 0.f;
#pragma unroll
        for (int j = 0; j < 8; j++) {
            float v = acc2[j][r];
            s1 += v; s2 += v * v;
        }
        s1 += __shfl_xor(s1, 1, 64);  s2 += __shfl_xor(s2, 1, 64);
        s1 += __shfl_xor(s1, 2, 64);  s2 += __shfl_xor(s2, 2, 64);
        s1 += __shfl_xor(s1, 4, 64);  s2 += __shfl_xor(s2, 4, 64);
        s1 += __shfl_xor(s1, 8, 64);  s2 += __shfl_xor(s2, 8, 64);
        float mu = s1 * (1.f / 128.f);
        float var = s2 * (1.f / 128.f) - mu * mu;
        float rinv = rsqrtf(fmaxf(var, 0.f) + 1e-5f);
        int gr = rowb + r;
        if (gr >= N) continue;
#pragma unroll
        for (int j = 0; j < 8; j++) {
            int col = j * 16 + l16;
            float v = acc2[j][r];
            x[(size_t)gr * D + col] = v;
            outB[(size_t)gr * D + col] = __float2bfloat16((v - mu) * rinv * lsv[j] + lbv[j]);
        }
    }
}

// ---------------- encoder stage 1: hb = bf16(relu(f@w1+b1)) ----------------
__global__ void k_enc1(const float* __restrict__ feat,
                       const float* __restrict__ w1, const float* __restrict__ b1,
                       bf16* __restrict__ hb, int N) {
    __shared__ float fsh[TN][DIN];
    int n0 = blockIdx.x * TN;
    int j = threadIdx.x;            // 0..127
    int nvalid = min(TN, N - n0);
    for (int idx = j; idx < TN * DIN; idx += 128) {
        int n = idx / DIN, i = idx % DIN;
        fsh[n][i] = (n < nvalid) ? feat[(n0 + n) * DIN + i] : 0.f;
    }
    __syncthreads();
    float bb = b1[j];
#pragma unroll
    for (int n = 0; n < TN; n++) {
        float a = bb;
#pragma unroll
        for (int i = 0; i < DIN; i++) a += fsh[n][i] * w1[i * D + j];
        if (n < nvalid) hb[(size_t)(n0 + n) * D + j] = __float2bfloat16(fmaxf(a, 0.f));
    }
}

// ---------------- attention: one wave per receiver, 16-edge window ----------
// CSR row preloaded in ONE coalesced load (lane L holds eid[r*64+L]);
// per-edge index comes from __shfl (VALU) instead of a memory load, so the
// gather address chain has no load->load hop. 2 slots x 8-deep = 16 edges
// in flight; 90% of waves (deg<=16) need a single gather round.
__device__ __forceinline__ void attn_edge(uint4 w, bool v, float4 qv,
                                          float& l, float& a0, float& a1,
                                          float& a2, float& a3) {
    float k0 = __uint_as_float(w.x << 16), v0 = __uint_as_float(w.x & 0xFFFF0000u);
    float k1 = __uint_as_float(w.y << 16), v1 = __uint_as_float(w.y & 0xFFFF0000u);
    float k2 = __uint_as_float(w.z << 16), v2 = __uint_as_float(w.z & 0xFFFF0000u);
    float k3 = __uint_as_float(w.w << 16), v3 = __uint_as_float(w.w & 0xFFFF0000u);
    float p = qv.x * k0 + qv.y * k1 + qv.z * k2 + qv.w * k3;
    p += __shfl_xor(p, 1, 64);
    p += __shfl_xor(p, 2, 64);
    p += __shfl_xor(p, 4, 64);
    float e = v ? exp2f(p) : 0.f;
    l += e;
    a0 += e * v0; a1 += e * v1; a2 += e * v2; a3 += e * v3;
}

__global__ __launch_bounds__(256) void k_attn(
        const bf16* __restrict__ qb, const uint* __restrict__ kvb,
        const int* __restrict__ deg, const int* __restrict__ eid,
        bf16* __restrict__ out, int N) {
    int wave = threadIdx.x >> 6, lane = threadIdx.x & 63;
    int r = blockIdx.x * 4 + wave;
    if (r >= N) return;
    int g = lane & 7;                    // dim group
    int h = (lane >> 3) & 3;             // head
    int slot = lane >> 5;                // edge slot 0..1
    int d0 = h * 32 + g * 4;

    // whole CSR row in one coalesced transaction
    int myidx = eid[(size_t)r * MAXDEG + lane];
    int cnt = min(deg[r], MAXDEG);

    uint2 qw = *(const uint2*)(qb + (size_t)r * D + d0);
    float4 qv;
    qv.x = __uint_as_float(qw.x << 16);
    qv.y = __uint_as_float(qw.x & 0xFFFF0000u);
    qv.z = __uint_as_float(qw.y << 16);
    qv.w = __uint_as_float(qw.y & 0xFFFF0000u);

    const uint* kvbase = kvb + d0;
    float l = 0.f, a0 = 0.f, a1 = 0.f, a2 = 0.f, a3 = 0.f;
    for (int base = 0; base < cnt; base += 16) {
        uint4 w[8];
        bool vv[8];
#pragma unroll
        for (int u = 0; u < 8; u++) {
            int e = base + u * 2 + slot;           // e <= 63 always
            vv[u] = e < cnt;
            int ss = __shfl(myidx, e, 64);
            ss = vv[u] ? ss : 0;
            w[u] = *(const uint4*)(kvbase + (size_t)ss * D);
        }
#pragma unroll
        for (int u = 0; u < 8; u++)
            attn_edge(w[u], vv[u], qv, l, a0, a1, a2, a3);
    }
    // combine the 2 edge slots (lane bit 5)
    l  += __shfl_xor(l, 32, 64);
    a0 += __shfl_xor(a0, 32, 64);
    a1 += __shfl_xor(a1, 32, 64);
    a2 += __shfl_xor(a2, 32, 64);
    a3 += __shfl_xor(a3, 32, 64);
    if (lane < 32) {
        float inv = 1.f / (l + 1e-9f);
        bf16 o[4];
        o[0] = __float2bfloat16(a0 * inv);
        o[1] = __float2bfloat16(a1 * inv);
        o[2] = __float2bfloat16(a2 * inv);
        o[3] = __float2bfloat16(a3 * inv);
        *(uint2*)(out + (size_t)r * D + d0) = *(uint2*)o;
    }
}

extern "C" void kernel_launch(void* const* d_in, const int* in_sizes, int n_in,
                              void* d_out, int out_size, void* d_ws, size_t ws_size,
                              hipStream_t stream) {
    const float* feat    = (const float*)d_in[0];
    const int*   senders = (const int*)d_in[1];
    const int*   recv    = (const int*)d_in[2];
    const float* enc_w1  = (const float*)d_in[3];
    const float* enc_b1  = (const float*)d_in[4];
    const float* enc_w2  = (const float*)d_in[5];
    const float* enc_b2  = (const float*)d_in[6];
    const float* wq      = (const float*)d_in[7];
    const float* wk      = (const float*)d_in[8];
    const float* wv      = (const float*)d_in[9];
    const float* wo      = (const float*)d_in[10];
    const float* ln1_s   = (const float*)d_in[11];
    const float* ln1_b   = (const float*)d_in[12];
    const float* ffn_w1  = (const float*)d_in[13];
    const float* ffn_b1  = (const float*)d_in[14];
    const float* ffn_w2  = (const float*)d_in[15];
    const float* ffn_b2  = (const float*)d_in[16];
    const float* ln2_s   = (const float*)d_in[17];
    const float* ln2_b   = (const float*)d_in[18];
    const float* dec_w1  = (const float*)d_in[19];
    const float* dec_b1  = (const float*)d_in[20];
    const float* dec_w2  = (const float*)d_in[21];
    const float* dec_b2  = (const float*)d_in[22];

    int N = in_sizes[0] / DIN;
    int E = in_sizes[1];

    // workspace layout
    char* p = (char*)d_ws;
    float* x   = (float*)p;  p += (size_t)N * D * 4;        // residual fp32
    bf16*  qb  = (bf16*)p;   p += (size_t)N * D * 2;        // q bf16 (pre-scaled)
    bf16*  kvb = (bf16*)p;   p += (size_t)N * D * 2 * 2;    // (k,v) bf16 interleaved
    bf16*  hb  = (bf16*)p;   p += (size_t)N * D * 2;        // LN out / attn out bf16
    int* deg   = (int*)p;    p += (size_t)N * 4;
    int* eid   = (int*)p;    p += (size_t)N * MAXDEG * 4;
    bf16* wqkvT  = (bf16*)p; p += (size_t)4 * 3 * D * D * 2;
    bf16* woT    = (bf16*)p; p += (size_t)4 * D * D * 2;
    bf16* w1T    = (bf16*)p; p += (size_t)4 * D * DFF * 2;
    bf16* w2T    = (bf16*)p; p += (size_t)4 * DFF * D * 2;
    bf16* encw2T = (bf16*)p; p += (size_t)D * D * 2;

    int gm = (N + BM - 1) / BM;   // 782

    k_wt<<<dim3(256, 26), 256, 0, stream>>>(wq, wk, wv, wo, ffn_w1, ffn_w2, enc_w2,
                                            wqkvT, woT, w1T, w2T, encw2T, deg, N);
    k_fill<<<(E + 255) / 256, 256, 0, stream>>>(recv, senders, deg, eid, E);
    k_enc1<<<(N + TN - 1) / TN, 128, 0, stream>>>(feat, enc_w1, enc_b1, hb, N);
    // x = hb @ enc_w2 + b2; hb = LN1_0(x)
    k_gemm<5><<<gm, 256, 0, stream>>>(hb, encw2T, enc_b2, ln1_s, ln1_b, x, hb, N);

    for (int l = 0; l < 4; l++) {
        k_qkv<<<gm, 256, 0, stream>>>(hb, wqkvT + (size_t)l * 3 * D * D, qb, kvb, N);
        k_attn<<<(N + 3) / 4, 256, 0, stream>>>(qb, (const uint*)kvb, deg, eid, hb, N);
        // x += hb @ wo; hb = LN2(x)
        k_gemm<2><<<gm, 256, 0, stream>>>(hb, woT + (size_t)l * D * D,
                                          nullptr, ln2_s + l * D, ln2_b + l * D,
                                          x, hb, N);
        // x += relu(hb@w1+b1)@w2 + b2; then LN1_{l+1} (l<3) or fused decode (l=3)
        if (l < 3)
            k_ffn<0><<<gm, 256, 0, stream>>>(hb, w1T + (size_t)l * D * DFF,
                                             ffn_b1 + l * DFF,
                                             w2T + (size_t)l * DFF * D, ffn_b2 + l * D,
                                             ln1_s + (l + 1) * D, ln1_b + (l + 1) * D,
                                             nullptr, nullptr, nullptr, nullptr,
                                             x, hb, nullptr, N);
        else
            k_ffn<1><<<gm, 256, 0, stream>>>(hb, w1T + (size_t)l * D * DFF,
                                             ffn_b1 + l * DFF,
                                             w2T + (size_t)l * DFF * D, ffn_b2 + l * D,
                                             nullptr, nullptr,
                                             dec_w1, dec_b1, dec_w2, dec_b2,
                                             x, nullptr, (float*)d_out, N);
    }
}

// Round 3
// 647.389 us; speedup vs baseline: 1.0488x; 1.0488x over previous
//
#include <hip/hip_runtime.h>
#include <hip/hip_bf16.h>
#include <math.h>

#define D     128
#define NHEAD 4
#define DH    32
#define DFF   512
#define DIN   16
#define MAXDEG 64
#define TN    16

typedef __attribute__((ext_vector_type(8))) short bf16x8;
typedef __attribute__((ext_vector_type(4))) float f32x4;
typedef __hip_bfloat16 bf16;

// 1/sqrt(32) * log2(e): q pre-scaled so attn weight = exp2(q.k)
#define QSCALE_L2E 0.2550348838f

// r13: A-fragments in 16 VGPRs straight from global; best dense config.
// r14: wo+ffn mega-fusion REGRESSED — dense chain is latency-plateau'd.
// r16: dispatch/traffic elimination outside inner loops works (+22 µs).
// r18: dense kernels rebuilt on global_load_lds + raw s_barrier + counted
//      vmcnt + XOR-swizzled linear LDS. 728->641 µs.
// r19: attn shfl-broadcast of CSR row REGRESSED (bpermute serial chain in
//      the index path) — reverted in r20. 16-edge window kept.
// r20 (this round): dense kernels latency-starved at 8 waves/CU (occ 18%,
//      MfmaUtil 6.7%). BM 64->128, 512 threads, 8 waves/block: 2x waves/CU,
//      grid 391 (< resident capacity, no tail). Stage loop reordered to
//      {BAR; prefetch; WAITV(counted); BAR} = true depth-2 in flight at
//      every wait (old order exposed full gll latency each stage).
//      launch_bounds(512,4) caps VGPR at 128 (measured 116) for 2 blocks/CU.
#define BM 128

#define WAITV(N) asm volatile("s_waitcnt vmcnt(" #N ")" ::: "memory")
#define WAITLGKM asm volatile("s_waitcnt lgkmcnt(0)" ::: "memory")
#define FENCE()  asm volatile("" ::: "memory")
#define BAR() do { FENCE(); __builtin_amdgcn_s_barrier(); FENCE(); } while (0)

__device__ __forceinline__ void gll16(const bf16* g, bf16* l) {
    __builtin_amdgcn_global_load_lds((__attribute__((address_space(1))) void*)g,
                                     (__attribute__((address_space(3))) void*)l,
                                     16, 0, 0);
}

__device__ __forceinline__ ushort bfbits(float f) {
    __hip_bfloat16 b = __float2bfloat16(f);
    return *(ushort*)&b;
}

// ---------------- CSR fill (deg zeroed by k_wt region 25) ----------------
__global__ void k_fill(const int* __restrict__ recv, const int* __restrict__ senders,
                       int* __restrict__ deg, int* __restrict__ eid, int E) {
    int e = blockIdx.x * blockDim.x + threadIdx.x;
    if (e >= E) return;
    int r = recv[e];
    int pos = atomicAdd(&deg[r], 1);
    if (pos < MAXDEG) eid[r * MAXDEG + pos] = senders[e];
}

// ---------------- weight transpose + bf16 convert + deg zero (26 regions) ----
__global__ void k_wt(const float* __restrict__ wq, const float* __restrict__ wk,
                     const float* __restrict__ wv, const float* __restrict__ wo,
                     const float* __restrict__ w1, const float* __restrict__ w2,
                     const float* __restrict__ encw2,
                     bf16* __restrict__ wqkvT, bf16* __restrict__ woT,
                     bf16* __restrict__ w1T, bf16* __restrict__ w2T,
                     bf16* __restrict__ encw2T, int* __restrict__ deg, int N) {
    int r = blockIdx.y;
    if (r == 25) {                       // zero deg (runs before k_fill)
        int i = blockIdx.x * blockDim.x + threadIdx.x;
        if (i < N) deg[i] = 0;
        return;
    }
    const float* src; bf16* dst; int K, Nout;
    if (r < 12) {
        int l = r / 3, sel = r % 3;
        src = (sel == 0 ? wq : sel == 1 ? wk : wv) + (size_t)l * D * D;
        dst = wqkvT + (size_t)l * 3 * D * D + (size_t)sel * D * D;
        K = D; Nout = D;
    } else if (r < 16) {
        int l = r - 12;
        src = wo + (size_t)l * D * D; dst = woT + (size_t)l * D * D; K = D; Nout = D;
    } else if (r < 20) {
        int l = r - 16;
        src = w1 + (size_t)l * D * DFF; dst = w1T + (size_t)l * D * DFF; K = D; Nout = DFF;
    } else if (r < 24) {
        int l = r - 20;
        src = w2 + (size_t)l * DFF * D; dst = w2T + (size_t)l * DFF * D; K = DFF; Nout = D;
    } else {
        src = encw2; dst = encw2T; K = D; Nout = D;
    }
    int total = K * Nout;
    int i = blockIdx.x * blockDim.x + threadIdx.x;
    if (i >= total) return;
    int k = i / Nout, j = i % Nout;
    dst[(size_t)j * K + k] = __float2bfloat16(src[i]);
}

// helper: load this wave's 4 A-fragments (16 rows x 128 cols) from global
__device__ __forceinline__ void load_afrag(const bf16* A, int arow, int quad,
                                           int N, bf16x8* afr) {
    const bf16* ab = A + (size_t)arow * D + quad * 8;
#pragma unroll
    for (int i = 0; i < 4; i++) {
        uint4 v = make_uint4(0u, 0u, 0u, 0u);
        if (arow < N) v = *(const uint4*)(ab + i * 32);
        afr[i] = *(bf16x8*)&v;
    }
}

// ---- stage a full 128x128 weight tile (32KB) via global_load_lds, 512t ----
// LDS linear [128][128]; granule(16B) swizzle: LDS (r,gL) <- src (r, gL^(r&15))
__device__ __forceinline__ void stage_full(bf16* lb, const bf16* src,
                                           int wave, int lane) {
#pragma unroll
    for (int k = 0; k < 4; k++) {
        int gidx = (wave * 4 + k) * 64 + lane;
        int r = gidx >> 4, gL = gidx & 15;
        gll16(src + (size_t)r * 128 + ((gL ^ (r & 15)) * 8),
              lb + (size_t)(wave * 4 + k) * 512);
    }
}

// ---- stage a 128x64 half-tile (16KB): LDS [128][64], mask 7, 512t ---------
__device__ __forceinline__ void stage_half(bf16* lb, const bf16* src, int rs,
                                           int wave, int lane) {
#pragma unroll
    for (int k = 0; k < 2; k++) {
        int gidx = (wave * 2 + k) * 64 + lane;
        int r = gidx >> 3, gL = gidx & 7;
        gll16(src + (size_t)r * rs + ((gL ^ (r & 7)) * 8),
              lb + (size_t)(wave * 2 + k) * 512);
    }
}

// MFMA over a full swizzled tile: acc[j] += A(afr) * W[128][128]
__device__ __forceinline__ void mfma_tile(const bf16* Wb, const bf16x8* afr,
                                          f32x4* acc, int l16, int quad) {
#pragma unroll
    for (int i = 0; i < 4; i++)
#pragma unroll
        for (int j = 0; j < 8; j++) {
            const bf16* wp = Wb + (size_t)(j * 16 + l16) * 128
                              + (size_t)((((i * 4 + quad)) ^ l16) * 8);
            acc[j] = __builtin_amdgcn_mfma_f32_16x16x32_bf16(afr[i], *(const bf16x8*)wp,
                                                             acc[j], 0, 0, 0);
        }
}

// ---------------- bf16 MFMA GEMM, 128 rows x 128 cols, K=128 ----------------
// OPs: 2 RES_LN (wo+ln2), 5 BIAS_LN (encode+ln1_0)
template<int OP>
__global__ __launch_bounds__(512, 4) void k_gemm(
        const bf16* __restrict__ A, const bf16* __restrict__ Bt,
        const float* __restrict__ bias,
        const float* __restrict__ lns, const float* __restrict__ lnb,
        float* x, bf16* outB, int N) {
    __shared__ alignas(16) bf16 Wsm[128 * 128];   // 32 KB
    int m0 = blockIdx.x * BM;
    int t = threadIdx.x;
    int wave = t >> 6, lane = t & 63;
    int quad = lane >> 4, l16 = lane & 15;
    int wm = wave * 16;

    bf16x8 afr[4];
    load_afrag(A, m0 + wm + l16, quad, N, afr);
    FENCE();
    stage_full(Wsm, Bt, wave, lane);
    WAITV(0); BAR();

    int rowb = m0 + wm + quad * 4;
    float xv[8][4];
    if (OP == 2) {   // hoist residual reads: latency hides under MFMA phase
#pragma unroll
        for (int j = 0; j < 8; j++)
#pragma unroll
            for (int r = 0; r < 4; r++) {
                int gr = rowb + r;
                xv[j][r] = (gr < N) ? x[(size_t)gr * D + j * 16 + l16] : 0.f;
            }
    }

    f32x4 acc[8];
#pragma unroll
    for (int j = 0; j < 8; j++) acc[j] = (f32x4){0.f, 0.f, 0.f, 0.f};
    mfma_tile(Wsm, afr, acc, l16, quad);

    float bv[8];
    if (OP == 5) {
#pragma unroll
        for (int j = 0; j < 8; j++) bv[j] = bias[j * 16 + l16];
    }
#pragma unroll
    for (int j = 0; j < 8; j++) {
#pragma unroll
        for (int r = 0; r < 4; r++) {
            int gr = rowb + r;
            if (gr >= N) continue;
            float val = acc[j][r];
            if (OP == 5) val += bv[j];
            if (OP == 2) val += xv[j][r];
            acc[j][r] = val;
        }
    }
    float lsv[8], lbv[8];
#pragma unroll
    for (int j = 0; j < 8; j++) {
        lsv[j] = lns[j * 16 + l16];
        lbv[j] = lnb[j * 16 + l16];
    }
#pragma unroll
    for (int r = 0; r < 4; r++) {
        float s1 = 0.f, s2 = 0.f;
#pragma unroll
        for (int j = 0; j < 8; j++) {
            float v = acc[j][r];
            s1 += v; s2 += v * v;
        }
        s1 += __shfl_xor(s1, 1, 64);  s2 += __shfl_xor(s2, 1, 64);
        s1 += __shfl_xor(s1, 2, 64);  s2 += __shfl_xor(s2, 2, 64);
        s1 += __shfl_xor(s1, 4, 64);  s2 += __shfl_xor(s2, 4, 64);
        s1 += __shfl_xor(s1, 8, 64);  s2 += __shfl_xor(s2, 8, 64);
        float mu = s1 * (1.f / 128.f);
        float var = s2 * (1.f / 128.f) - mu * mu;
        float rinv = rsqrtf(fmaxf(var, 0.f) + 1e-5f);
        int gr = rowb + r;
        if (gr >= N) continue;
#pragma unroll
        for (int j = 0; j < 8; j++) {
            int col = j * 16 + l16;
            float v = acc[j][r];
            x[(size_t)gr * D + col] = v;
            outB[(size_t)gr * D + col] =
                __float2bfloat16((v - mu) * rinv * lsv[j] + lbv[j]);
        }
    }
}

// ---------------- fused QKV: double-buffered gll pipeline, 512t -------------
__global__ __launch_bounds__(512, 4) void k_qkv(
        const bf16* __restrict__ hb, const bf16* __restrict__ wqkvT,
        bf16* __restrict__ qb, bf16* __restrict__ kvb, int N) {
    __shared__ alignas(16) bf16 Wbuf[2][128 * 128];   // 64 KB -> 2 blocks/CU
    int m0 = blockIdx.x * BM;
    int t = threadIdx.x;
    int wave = t >> 6, lane = t & 63;
    int quad = lane >> 4, l16 = lane & 15;
    int wm = wave * 16;

    bf16x8 afr[4];
    load_afrag(hb, m0 + wm + l16, quad, N, afr);
    FENCE();
    stage_full(Wbuf[0], wqkvT, wave, lane);               // q tile
    FENCE();
    stage_full(Wbuf[1], wqkvT + (size_t)D * D, wave, lane); // k tile
    FENCE();

    f32x4 aq[8], ak[8], av[8];
#pragma unroll
    for (int j = 0; j < 8; j++) aq[j] = (f32x4){0.f, 0.f, 0.f, 0.f};

    WAITV(4); BAR();                 // afr+q ready (k in flight)
    __builtin_amdgcn_s_setprio(1);
    mfma_tile(Wbuf[0], afr, aq, l16, quad);
    __builtin_amdgcn_s_setprio(0);
    BAR();                           // buf0 free
    stage_full(Wbuf[0], wqkvT + (size_t)2 * D * D, wave, lane);  // v tile
    FENCE();
    WAITV(4); BAR();                 // k ready (v in flight)
#pragma unroll
    for (int j = 0; j < 8; j++) ak[j] = (f32x4){0.f, 0.f, 0.f, 0.f};
    __builtin_amdgcn_s_setprio(1);
    mfma_tile(Wbuf[1], afr, ak, l16, quad);
    __builtin_amdgcn_s_setprio(0);
    WAITV(0); BAR();                 // v ready (all waves)
#pragma unroll
    for (int j = 0; j < 8; j++) av[j] = (f32x4){0.f, 0.f, 0.f, 0.f};
    __builtin_amdgcn_s_setprio(1);
    mfma_tile(Wbuf[0], afr, av, l16, quad);
    __builtin_amdgcn_s_setprio(0);

    int rowb = m0 + wm + quad * 4;
#pragma unroll
    for (int j = 0; j < 8; j++) {
        int col = j * 16 + l16;
#pragma unroll
        for (int r = 0; r < 4; r++) {
            int gr = rowb + r;
            if (gr >= N) continue;
            qb[(size_t)gr * D + col] = __float2bfloat16(aq[j][r] * QSCALE_L2E);
            uint kv = (uint)bfbits(ak[j][r]) | ((uint)bfbits(av[j][r]) << 16);
            *(uint*)&kvb[((size_t)gr * D + col) * 2] = kv;
        }
    }
}

// ---- stage FFN subtile ts (0..15): per c: {W1 h0, W1 h1, W2 h0, W2 h1} ----
__device__ __forceinline__ void stage_ffn_tile(int ts, const bf16* w1T,
                                               const bf16* w2T, bf16* Wb3,
                                               int wave, int lane) {
    int c = ts >> 2, ph = ts & 3;
    const bf16* src; int rs;
    if (ph < 2) { src = w1T + (size_t)(c * 128) * 128 + ph * 64; rs = 128; }
    else        { src = w2T + c * 128 + (ph - 2) * 64;           rs = DFF; }
    stage_half(Wb3 + (size_t)(ts % 3) * (64 * 128), src, rs, wave, lane);
}

// ---------------- fused FFN: 16-stage gll pipeline, ring of 3 subtiles ------
// x += relu(hb@w1+b1)@w2 + b2; then LN (MODE 0) or fused decode (MODE 1)
template<int MODE>
__global__ __launch_bounds__(512, 4) void k_ffn(
        const bf16* __restrict__ hb, const bf16* __restrict__ w1T,
        const float* __restrict__ b1,
        const bf16* __restrict__ w2T, const float* __restrict__ b2,
        const float* __restrict__ lns, const float* __restrict__ lnb,
        const float* __restrict__ dw1, const float* __restrict__ db1,
        const float* __restrict__ dw2, const float* __restrict__ db2,
        float* x, bf16* outB, float* out, int N) {
    __shared__ alignas(16) bf16 Wb3[3][64 * 128];   // 48 KB ring
    __shared__ alignas(16) bf16 Hsm[128 * 128];     // 32 KB (swizzled) => 80 KB
    int m0 = blockIdx.x * BM;
    int t = threadIdx.x;
    int wave = t >> 6, lane = t & 63;
    int quad = lane >> 4, l16 = lane & 15;
    int wm = wave * 16;
    int rowb = m0 + wm + quad * 4;

    // preload all b1 biases: keeps the pipeline free of stray vmem ops
    float b1pre[4][8];
#pragma unroll
    for (int c2 = 0; c2 < 4; c2++)
#pragma unroll
        for (int j = 0; j < 8; j++) b1pre[c2][j] = b1[c2 * 128 + j * 16 + l16];

    bf16x8 afr[4];
    load_afrag(hb, m0 + wm + l16, quad, N, afr);
    FENCE();
    stage_ffn_tile(0, w1T, w2T, &Wb3[0][0], wave, lane);
    FENCE();
    stage_ffn_tile(1, w1T, w2T, &Wb3[0][0], wave, lane);
    FENCE();

    f32x4 acc2[8], accP[8];
#pragma unroll
    for (int j = 0; j < 8; j++) acc2[j] = (f32x4){0.f, 0.f, 0.f, 0.f};
    float xv[8][4];

#pragma unroll
    for (int s = 0; s < 16; s++) {
        BAR();                       // all waves done reading tile s-1's slot
        if (s + 2 < 16) {
            stage_ffn_tile(s + 2, w1T, w2T, &Wb3[0][0], wave, lane);
            FENCE();
        }
        // tile s done (own parts); s+1, s+2 remain in flight (2 ops each)
        if (s < 14) { WAITV(4); } else if (s == 14) { WAITV(2); } else { WAITV(0); }
        BAR();                       // everyone's parts of tile s landed
        const bf16* Wb = &Wb3[0][0] + (size_t)(s % 3) * (64 * 128);
        int c = s >> 2, ph = s & 3;
        if (s == 15) {   // residual prefetch: hides under last stage + epilogue
#pragma unroll
            for (int j = 0; j < 8; j++)
#pragma unroll
                for (int r = 0; r < 4; r++) {
                    int gr = rowb + r;
                    xv[j][r] = (gr < N) ? x[(size_t)gr * D + j * 16 + l16] : 0.f;
                }
        }
        if (ph < 2) {
            if (ph == 0) {
#pragma unroll
                for (int j = 0; j < 8; j++) accP[j] = (f32x4){0.f, 0.f, 0.f, 0.f};
            }
            __builtin_amdgcn_s_setprio(1);
#pragma unroll
            for (int i2 = 0; i2 < 2; i2++) {
#pragma unroll
                for (int j = 0; j < 8; j++) {
                    const bf16* wp = Wb + (size_t)(j * 16 + l16) * 64
                                      + (size_t)(((i2 * 4 + quad) ^ (l16 & 7)) * 8);
                    accP[j] = __builtin_amdgcn_mfma_f32_16x16x32_bf16(
                        afr[ph * 2 + i2], *(const bf16x8*)wp, accP[j], 0, 0, 0);
                }
            }
            __builtin_amdgcn_s_setprio(0);
            if (ph == 1) {   // relu+bias -> swizzled Hsm (wave-private rows)
                int rw = wm + quad * 4;
#pragma unroll
                for (int j = 0; j < 8; j++) {
                    int gb = j * 2 + (l16 >> 3), ce = l16 & 7;
#pragma unroll
                    for (int r = 0; r < 4; r++) {
                        int row = rw + r;
                        Hsm[(size_t)row * 128 + (size_t)((gb ^ (row & 15)) * 8) + ce] =
                            __float2bfloat16(fmaxf(accP[j][r] + b1pre[c][j], 0.f));
                    }
                }
                WAITLGKM;   // own ds_writes drained before next-stage reads
            }
        } else {
            int h = ph - 2;
            __builtin_amdgcn_s_setprio(1);
#pragma unroll
            for (int k2 = 0; k2 < 2; k2++) {
                int ks = h * 2 + k2;
                const bf16* hp = Hsm + (size_t)(wm + l16) * 128
                                  + (size_t)(((ks * 4 + quad) ^ l16) * 8);
                bf16x8 af2 = *(const bf16x8*)hp;
#pragma unroll
                for (int j = 0; j < 8; j++) {
                    const bf16* wp = Wb + (size_t)(j * 16 + l16) * 64
                                      + (size_t)(((k2 * 4 + quad) ^ (l16 & 7)) * 8);
                    acc2[j] = __builtin_amdgcn_mfma_f32_16x16x32_bf16(
                        af2, *(const bf16x8*)wp, acc2[j], 0, 0, 0);
                }
            }
            __builtin_amdgcn_s_setprio(0);
        }
    }

    float bv[8];
#pragma unroll
    for (int j = 0; j < 8; j++) bv[j] = b2[j * 16 + l16];
#pragma unroll
    for (int j = 0; j < 8; j++) {
#pragma unroll
        for (int r = 0; r < 4; r++) {
            int gr = rowb + r;
            if (gr >= N) continue;
            acc2[j][r] += bv[j] + xv[j][r];
        }
    }
    if (MODE == 1) {
        float dw[8][3];
#pragma unroll
        for (int j = 0; j < 8; j++) {
            int col = j * 16 + l16;
#pragma unroll
            for (int cc3 = 0; cc3 < 3; cc3++) dw[j][cc3] = dw1[col * 3 + cc3];
        }
#pragma unroll
        for (int r = 0; r < 4; r++) {
            float s0 = 0.f, s1 = 0.f, s2 = 0.f;
#pragma unroll
            for (int j = 0; j < 8; j++) {
                float v = acc2[j][r];
                s0 += v * dw[j][0]; s1 += v * dw[j][1]; s2 += v * dw[j][2];
            }
            s0 += __shfl_xor(s0, 1, 64); s1 += __shfl_xor(s1, 1, 64); s2 += __shfl_xor(s2, 1, 64);
            s0 += __shfl_xor(s0, 2, 64); s1 += __shfl_xor(s1, 2, 64); s2 += __shfl_xor(s2, 2, 64);
            s0 += __shfl_xor(s0, 4, 64); s1 += __shfl_xor(s1, 4, 64); s2 += __shfl_xor(s2, 4, 64);
            s0 += __shfl_xor(s0, 8, 64); s1 += __shfl_xor(s1, 8, 64); s2 += __shfl_xor(s2, 8, 64);
            int gr = rowb + r;
            if (l16 == 0 && gr < N) {
                float t0 = fmaxf(s0 + db1[0], 0.f);
                float t1 = fmaxf(s1 + db1[1], 0.f);
                float t2 = fmaxf(s2 + db1[2], 0.f);
#pragma unroll
                for (int o = 0; o < 3; o++)
                    out[(size_t)gr * 3 + o] =
                        t0 * dw2[0 * 3 + o] + t1 * dw2[1 * 3 + o] + t2 * dw2[2 * 3 + o] + db2[o];
            }
        }
        return;
    }
    float lsv[8], lbv[8];
#pragma unroll
    for (int j = 0; j < 8; j++) {
        lsv[j] = lns[j * 16 + l16];
        lbv[j] = lnb[j * 16 + l16];
    }
#pragma unroll
    for (int r = 0; r < 4; r++) {
        float s1 = 0.f, s2 = 0.f;
#pragma unroll
        for (int j = 0; j < 8; j++) {
            float v = acc2[j][r];
            s1 += v; s2 += v * v;
        }
        s1 += __shfl_xor(s1, 1, 64);  s2 += __shfl_xor(s2, 1, 64);
        s1 += __shfl_xor(s1, 2, 64);  s2 += __shfl_xor(s2, 2, 64);
        s1 += __shfl_xor(s1, 4, 64);  s2 += __shfl_xor(s2, 4, 64);
        s1 += __shfl_xor(s1, 8, 64);  s2 += __shfl_xor(s2, 8, 64);
        float mu = s1 * (1.f / 128.f);
        float var = s2 * (1.f / 128.f) - mu * mu;
        float rinv = rsqrtf(fmaxf(var, 0.f) + 1e-5f);
        int gr = rowb + r;
        if (gr >= N) continue;
#pragma unroll
        for (int j = 0; j < 8; j++) {
            int col = j * 16 + l16;
            float v = acc2[j][r];
            x[(size_t)gr * D + col] = v;
            outB[(size_t)gr * D + col] = __float2bfloat16((v - mu) * rinv * lsv[j] + lbv[j]);
        }
    }
}

// ---------------- encoder stage 1: hb = bf16(relu(f@w1+b1)) ----------------
__global__ void k_enc1(const float* __restrict__ feat,
                       const float* __restrict__ w1, const float* __restrict__ b1,
                       bf16* __restrict__ hb, int N) {
    __shared__ float fsh[TN][DIN];
    int n0 = blockIdx.x * TN;
    int j = threadIdx.x;            // 0..127
    int nvalid = min(TN, N - n0);
    for (int idx = j; idx < TN * DIN; idx += 128) {
        int n = idx / DIN, i = idx % DIN;
        fsh[n][i] = (n < nvalid) ? feat[(n0 + n) * DIN + i] : 0.f;
    }
    __syncthreads();
    float bb = b1[j];
#pragma unroll
    for (int n = 0; n < TN; n++) {
        float a = bb;
#pragma unroll
        for (int i = 0; i < DIN; i++) a += fsh[n][i] * w1[i * D + j];
        if (n < nvalid) hb[(size_t)(n0 + n) * D + j] = __float2bfloat16(fmaxf(a, 0.f));
    }
}

// ---------------- attention: one wave per receiver, 16-edge window ----------
// Direct per-edge index loads (r19's shfl broadcast regressed); 2 slots x
// 8-deep = 16 edges in flight; 90% of waves (deg<=16) need one gather round.
__device__ __forceinline__ void attn_edge(uint4 w, bool v, float4 qv,
                                          float& l, float& a0, float& a1,
                                          float& a2, float& a3) {
    float k0 = __uint_as_float(w.x << 16), v0 = __uint_as_float(w.x & 0xFFFF0000u);
    float k1 = __uint_as_float(w.y << 16), v1 = __uint_as_float(w.y & 0xFFFF0000u);
    float k2 = __uint_as_float(w.z << 16), v2 = __uint_as_float(w.z & 0xFFFF0000u);
    float k3 = __uint_as_float(w.w << 16), v3 = __uint_as_float(w.w & 0xFFFF0000u);
    float p = qv.x * k0 + qv.y * k1 + qv.z * k2 + qv.w * k3;
    p += __shfl_xor(p, 1, 64);
    p += __shfl_xor(p, 2, 64);
    p += __shfl_xor(p, 4, 64);
    float e = v ? exp2f(p) : 0.f;
    l += e;
    a0 += e * v0; a1 += e * v1; a2 += e * v2; a3 += e * v3;
}

__global__ __launch_bounds__(256) void k_attn(
        const bf16* __restrict__ qb, const uint* __restrict__ kvb,
        const int* __restrict__ deg, const int* __restrict__ eid,
        bf16* __restrict__ out, int N) {
    int wave = threadIdx.x >> 6, lane = threadIdx.x & 63;
    int r = blockIdx.x * 4 + wave;
    if (r >= N) return;
    int g = lane & 7;                    // dim group
    int h = (lane >> 3) & 3;             // head
    int slot = lane >> 5;                // edge slot 0..1
    int d0 = h * 32 + g * 4;
    uint2 qw = *(const uint2*)(qb + (size_t)r * D + d0);
    float4 qv;
    qv.x = __uint_as_float(qw.x << 16);
    qv.y = __uint_as_float(qw.x & 0xFFFF0000u);
    qv.z = __uint_as_float(qw.y << 16);
    qv.w = __uint_as_float(qw.y & 0xFFFF0000u);
    int cnt = min(deg[r], MAXDEG);
    const int* row = eid + (size_t)r * MAXDEG;
    const uint* kvbase = kvb + d0;
    float l = 0.f, a0 = 0.f, a1 = 0.f, a2 = 0.f, a3 = 0.f;
    for (int base = 0; base < cnt; base += 16) {
        int ss[8];
        bool vv[8];
#pragma unroll
        for (int u = 0; u < 8; u++) {
            int e = base + u * 2 + slot;
            vv[u] = e < cnt;
            ss[u] = vv[u] ? row[e] : 0;
        }
        uint4 w[8];
#pragma unroll
        for (int u = 0; u < 8; u++)
            w[u] = *(const uint4*)(kvbase + (size_t)ss[u] * D);
#pragma unroll
        for (int u = 0; u < 8; u++)
            attn_edge(w[u], vv[u], qv, l, a0, a1, a2, a3);
    }
    // combine the 2 edge slots (lane bit 5)
    l  += __shfl_xor(l, 32, 64);
    a0 += __shfl_xor(a0, 32, 64);
    a1 += __shfl_xor(a1, 32, 64);
    a2 += __shfl_xor(a2, 32, 64);
    a3 += __shfl_xor(a3, 32, 64);
    if (lane < 32) {
        float inv = 1.f / (l + 1e-9f);
        bf16 o[4];
        o[0] = __float2bfloat16(a0 * inv);
        o[1] = __float2bfloat16(a1 * inv);
        o[2] = __float2bfloat16(a2 * inv);
        o[3] = __float2bfloat16(a3 * inv);
        *(uint2*)(out + (size_t)r * D + d0) = *(uint2*)o;
    }
}

extern "C" void kernel_launch(void* const* d_in, const int* in_sizes, int n_in,
                              void* d_out, int out_size, void* d_ws, size_t ws_size,
                              hipStream_t stream) {
    const float* feat    = (const float*)d_in[0];
    const int*   senders = (const int*)d_in[1];
    const int*   recv    = (const int*)d_in[2];
    const float* enc_w1  = (const float*)d_in[3];
    const float* enc_b1  = (const float*)d_in[4];
    const float* enc_w2  = (const float*)d_in[5];
    const float* enc_b2  = (const float*)d_in[6];
    const float* wq      = (const float*)d_in[7];
    const float* wk      = (const float*)d_in[8];
    const float* wv      = (const float*)d_in[9];
    const float* wo      = (const float*)d_in[10];
    const float* ln1_s   = (const float*)d_in[11];
    const float* ln1_b   = (const float*)d_in[12];
    const float* ffn_w1  = (const float*)d_in[13];
    const float* ffn_b1  = (const float*)d_in[14];
    const float* ffn_w2  = (const float*)d_in[15];
    const float* ffn_b2  = (const float*)d_in[16];
    const float* ln2_s   = (const float*)d_in[17];
    const float* ln2_b   = (const float*)d_in[18];
    const float* dec_w1  = (const float*)d_in[19];
    const float* dec_b1  = (const float*)d_in[20];
    const float* dec_w2  = (const float*)d_in[21];
    const float* dec_b2  = (const float*)d_in[22];

    int N = in_sizes[0] / DIN;
    int E = in_sizes[1];

    // workspace layout
    char* p = (char*)d_ws;
    float* x   = (float*)p;  p += (size_t)N * D * 4;        // residual fp32
    bf16*  qb  = (bf16*)p;   p += (size_t)N * D * 2;        // q bf16 (pre-scaled)
    bf16*  kvb = (bf16*)p;   p += (size_t)N * D * 2 * 2;    // (k,v) bf16 interleaved
    bf16*  hb  = (bf16*)p;   p += (size_t)N * D * 2;        // LN out / attn out bf16
    int* deg   = (int*)p;    p += (size_t)N * 4;
    int* eid   = (int*)p;    p += (size_t)N * MAXDEG * 4;
    bf16* wqkvT  = (bf16*)p; p += (size_t)4 * 3 * D * D * 2;
    bf16* woT    = (bf16*)p; p += (size_t)4 * D * D * 2;
    bf16* w1T    = (bf16*)p; p += (size_t)4 * D * DFF * 2;
    bf16* w2T    = (bf16*)p; p += (size_t)4 * DFF * D * 2;
    bf16* encw2T = (bf16*)p; p += (size_t)D * D * 2;

    int gm = (N + BM - 1) / BM;   // 391

    k_wt<<<dim3(256, 26), 256, 0, stream>>>(wq, wk, wv, wo, ffn_w1, ffn_w2, enc_w2,
                                            wqkvT, woT, w1T, w2T, encw2T, deg, N);
    k_fill<<<(E + 255) / 256, 256, 0, stream>>>(recv, senders, deg, eid, E);
    k_enc1<<<(N + TN - 1) / TN, 128, 0, stream>>>(feat, enc_w1, enc_b1, hb, N);
    // x = hb @ enc_w2 + b2; hb = LN1_0(x)
    k_gemm<5><<<gm, 512, 0, stream>>>(hb, encw2T, enc_b2, ln1_s, ln1_b, x, hb, N);

    for (int l = 0; l < 4; l++) {
        k_qkv<<<gm, 512, 0, stream>>>(hb, wqkvT + (size_t)l * 3 * D * D, qb, kvb, N);
        k_attn<<<(N + 3) / 4, 256, 0, stream>>>(qb, (const uint*)kvb, deg, eid, hb, N);
        // x += hb @ wo; hb = LN2(x)
        k_gemm<2><<<gm, 512, 0, stream>>>(hb, woT + (size_t)l * D * D,
                                          nullptr, ln2_s + l * D, ln2_b + l * D,
                                          x, hb, N);
        // x += relu(hb@w1+b1)@w2 + b2; then LN1_{l+1} (l<3) or fused decode (l=3)
        if (l < 3)
            k_ffn<0><<<gm, 512, 0, stream>>>(hb, w1T + (size_t)l * D * DFF,
                                             ffn_b1 + l * DFF,
                                             w2T + (size_t)l * DFF * D, ffn_b2 + l * D,
                                             ln1_s + (l + 1) * D, ln1_b + (l + 1) * D,
                                             nullptr, nullptr, nullptr, nullptr,
                                             x, hb, nullptr, N);
        else
            k_ffn<1><<<gm, 512, 0, stream>>>(hb, w1T + (size_t)l * D * DFF,
                                             ffn_b1 + l * DFF,
                                             w2T + (size_t)l * DFF * D, ffn_b2 + l * D,
                                             nullptr, nullptr,
                                             dec_w1, dec_b1, dec_w2, dec_b2,
                                             x, nullptr, (float*)d_out, N);
    }
}

// Round 4
// 611.597 us; speedup vs baseline: 1.1102x; 1.0585x over previous
//
#include <hip/hip_runtime.h>
#include <hip/hip_bf16.h>
#include <math.h>

#define D     128
#define NHEAD 4
#define DH    32
#define DFF   512
#define DIN   16
#define MAXDEG 64
#define TN    16

typedef __attribute__((ext_vector_type(8))) short bf16x8;
typedef __attribute__((ext_vector_type(4))) float f32x4;
typedef __hip_bfloat16 bf16;

// 1/sqrt(32) * log2(e): q pre-scaled so attn weight = exp2(q.k)
#define QSCALE_L2E 0.2550348838f

// r13: A-fragments in 16 VGPRs straight from global; best dense config.
// r14: wo+ffn mega-fusion REGRESSED — dense chain is latency-plateau'd.
// r16: dispatch/traffic elimination outside inner loops works (+22 µs).
// r18: dense kernels rebuilt on global_load_lds + raw s_barrier + counted
//      vmcnt + XOR-swizzled linear LDS. 728->641 µs.
// r19: attn shfl-broadcast of CSR row REGRESSED (bpermute serial chain).
// r20: BM 64->128, 512t, depth-2 stage pipeline. k_ffn 71->53 µs DESPITE:
// r21 (this round): (512,4) capped VGPR at 64 -> ~280B/thread scratch spill
//      (k_ffn WRITE_SIZE 37.5->93.5 MB, FETCH 20->48 MB). At 512t the 2nd
//      launch_bounds arg empirically acts as min-BLOCKS/CU. Fix: (512,2)
//      (cap >=128, demand ~116). k_qkv restructured to <=2 live acc sets
//      (K->V->Q order, kv packed+stored after V, q stored last) so it fits
//      regardless; counted waits stay exact (last block drains WAITV(0)).
#define BM 128

#define WAITV(N) asm volatile("s_waitcnt vmcnt(" #N ")" ::: "memory")
#define WAITLGKM asm volatile("s_waitcnt lgkmcnt(0)" ::: "memory")
#define FENCE()  asm volatile("" ::: "memory")
#define BAR() do { FENCE(); __builtin_amdgcn_s_barrier(); FENCE(); } while (0)

__device__ __forceinline__ void gll16(const bf16* g, bf16* l) {
    __builtin_amdgcn_global_load_lds((__attribute__((address_space(1))) void*)g,
                                     (__attribute__((address_space(3))) void*)l,
                                     16, 0, 0);
}

__device__ __forceinline__ ushort bfbits(float f) {
    __hip_bfloat16 b = __float2bfloat16(f);
    return *(ushort*)&b;
}

// ---------------- CSR fill (deg zeroed by k_wt region 25) ----------------
__global__ void k_fill(const int* __restrict__ recv, const int* __restrict__ senders,
                       int* __restrict__ deg, int* __restrict__ eid, int E) {
    int e = blockIdx.x * blockDim.x + threadIdx.x;
    if (e >= E) return;
    int r = recv[e];
    int pos = atomicAdd(&deg[r], 1);
    if (pos < MAXDEG) eid[r * MAXDEG + pos] = senders[e];
}

// ---------------- weight transpose + bf16 convert + deg zero (26 regions) ----
__global__ void k_wt(const float* __restrict__ wq, const float* __restrict__ wk,
                     const float* __restrict__ wv, const float* __restrict__ wo,
                     const float* __restrict__ w1, const float* __restrict__ w2,
                     const float* __restrict__ encw2,
                     bf16* __restrict__ wqkvT, bf16* __restrict__ woT,
                     bf16* __restrict__ w1T, bf16* __restrict__ w2T,
                     bf16* __restrict__ encw2T, int* __restrict__ deg, int N) {
    int r = blockIdx.y;
    if (r == 25) {                       // zero deg (runs before k_fill)
        int i = blockIdx.x * blockDim.x + threadIdx.x;
        if (i < N) deg[i] = 0;
        return;
    }
    const float* src; bf16* dst; int K, Nout;
    if (r < 12) {
        int l = r / 3, sel = r % 3;
        src = (sel == 0 ? wq : sel == 1 ? wk : wv) + (size_t)l * D * D;
        dst = wqkvT + (size_t)l * 3 * D * D + (size_t)sel * D * D;
        K = D; Nout = D;
    } else if (r < 16) {
        int l = r - 12;
        src = wo + (size_t)l * D * D; dst = woT + (size_t)l * D * D; K = D; Nout = D;
    } else if (r < 20) {
        int l = r - 16;
        src = w1 + (size_t)l * D * DFF; dst = w1T + (size_t)l * D * DFF; K = D; Nout = DFF;
    } else if (r < 24) {
        int l = r - 20;
        src = w2 + (size_t)l * DFF * D; dst = w2T + (size_t)l * DFF * D; K = DFF; Nout = D;
    } else {
        src = encw2; dst = encw2T; K = D; Nout = D;
    }
    int total = K * Nout;
    int i = blockIdx.x * blockDim.x + threadIdx.x;
    if (i >= total) return;
    int k = i / Nout, j = i % Nout;
    dst[(size_t)j * K + k] = __float2bfloat16(src[i]);
}

// helper: load this wave's 4 A-fragments (16 rows x 128 cols) from global
__device__ __forceinline__ void load_afrag(const bf16* A, int arow, int quad,
                                           int N, bf16x8* afr) {
    const bf16* ab = A + (size_t)arow * D + quad * 8;
#pragma unroll
    for (int i = 0; i < 4; i++) {
        uint4 v = make_uint4(0u, 0u, 0u, 0u);
        if (arow < N) v = *(const uint4*)(ab + i * 32);
        afr[i] = *(bf16x8*)&v;
    }
}

// ---- stage a full 128x128 weight tile (32KB) via global_load_lds, 512t ----
// LDS linear [128][128]; granule(16B) swizzle: LDS (r,gL) <- src (r, gL^(r&15))
__device__ __forceinline__ void stage_full(bf16* lb, const bf16* src,
                                           int wave, int lane) {
#pragma unroll
    for (int k = 0; k < 4; k++) {
        int gidx = (wave * 4 + k) * 64 + lane;
        int r = gidx >> 4, gL = gidx & 15;
        gll16(src + (size_t)r * 128 + ((gL ^ (r & 15)) * 8),
              lb + (size_t)(wave * 4 + k) * 512);
    }
}

// ---- stage a 128x64 half-tile (16KB): LDS [128][64], mask 7, 512t ---------
__device__ __forceinline__ void stage_half(bf16* lb, const bf16* src, int rs,
                                           int wave, int lane) {
#pragma unroll
    for (int k = 0; k < 2; k++) {
        int gidx = (wave * 2 + k) * 64 + lane;
        int r = gidx >> 3, gL = gidx & 7;
        gll16(src + (size_t)r * rs + ((gL ^ (r & 7)) * 8),
              lb + (size_t)(wave * 2 + k) * 512);
    }
}

// MFMA over a full swizzled tile: acc[j] += A(afr) * W[128][128]
__device__ __forceinline__ void mfma_tile(const bf16* Wb, const bf16x8* afr,
                                          f32x4* acc, int l16, int quad) {
#pragma unroll
    for (int i = 0; i < 4; i++)
#pragma unroll
        for (int j = 0; j < 8; j++) {
            const bf16* wp = Wb + (size_t)(j * 16 + l16) * 128
                              + (size_t)((((i * 4 + quad)) ^ l16) * 8);
            acc[j] = __builtin_amdgcn_mfma_f32_16x16x32_bf16(afr[i], *(const bf16x8*)wp,
                                                             acc[j], 0, 0, 0);
        }
}

// ---------------- bf16 MFMA GEMM, 128 rows x 128 cols, K=128 ----------------
// OPs: 2 RES_LN (wo+ln2), 5 BIAS_LN (encode+ln1_0)
template<int OP>
__global__ __launch_bounds__(512, 2) void k_gemm(
        const bf16* __restrict__ A, const bf16* __restrict__ Bt,
        const float* __restrict__ bias,
        const float* __restrict__ lns, const float* __restrict__ lnb,
        float* x, bf16* outB, int N) {
    __shared__ alignas(16) bf16 Wsm[128 * 128];   // 32 KB
    int m0 = blockIdx.x * BM;
    int t = threadIdx.x;
    int wave = t >> 6, lane = t & 63;
    int quad = lane >> 4, l16 = lane & 15;
    int wm = wave * 16;

    bf16x8 afr[4];
    load_afrag(A, m0 + wm + l16, quad, N, afr);
    FENCE();
    stage_full(Wsm, Bt, wave, lane);
    WAITV(0); BAR();

    int rowb = m0 + wm + quad * 4;
    float xv[8][4];
    if (OP == 2) {   // hoist residual reads: latency hides under MFMA phase
#pragma unroll
        for (int j = 0; j < 8; j++)
#pragma unroll
            for (int r = 0; r < 4; r++) {
                int gr = rowb + r;
                xv[j][r] = (gr < N) ? x[(size_t)gr * D + j * 16 + l16] : 0.f;
            }
    }

    f32x4 acc[8];
#pragma unroll
    for (int j = 0; j < 8; j++) acc[j] = (f32x4){0.f, 0.f, 0.f, 0.f};
    mfma_tile(Wsm, afr, acc, l16, quad);

    float bv[8];
    if (OP == 5) {
#pragma unroll
        for (int j = 0; j < 8; j++) bv[j] = bias[j * 16 + l16];
    }
#pragma unroll
    for (int j = 0; j < 8; j++) {
#pragma unroll
        for (int r = 0; r < 4; r++) {
            int gr = rowb + r;
            if (gr >= N) continue;
            float val = acc[j][r];
            if (OP == 5) val += bv[j];
            if (OP == 2) val += xv[j][r];
            acc[j][r] = val;
        }
    }
    float lsv[8], lbv[8];
#pragma unroll
    for (int j = 0; j < 8; j++) {
        lsv[j] = lns[j * 16 + l16];
        lbv[j] = lnb[j * 16 + l16];
    }
#pragma unroll
    for (int r = 0; r < 4; r++) {
        float s1 = 0.f, s2 = 0.f;
#pragma unroll
        for (int j = 0; j < 8; j++) {
            float v = acc[j][r];
            s1 += v; s2 += v * v;
        }
        s1 += __shfl_xor(s1, 1, 64);  s2 += __shfl_xor(s2, 1, 64);
        s1 += __shfl_xor(s1, 2, 64);  s2 += __shfl_xor(s2, 2, 64);
        s1 += __shfl_xor(s1, 4, 64);  s2 += __shfl_xor(s2, 4, 64);
        s1 += __shfl_xor(s1, 8, 64);  s2 += __shfl_xor(s2, 8, 64);
        float mu = s1 * (1.f / 128.f);
        float var = s2 * (1.f / 128.f) - mu * mu;
        float rinv = rsqrtf(fmaxf(var, 0.f) + 1e-5f);
        int gr = rowb + r;
        if (gr >= N) continue;
#pragma unroll
        for (int j = 0; j < 8; j++) {
            int col = j * 16 + l16;
            float v = acc[j][r];
            x[(size_t)gr * D + col] = v;
            outB[(size_t)gr * D + col] =
                __float2bfloat16((v - mu) * rinv * lsv[j] + lbv[j]);
        }
    }
}

// ---------------- fused QKV: K->V->Q phases, <=2 live acc sets --------------
// kv packed+stored right after V-MFMA (overlaps Q-tile gll); q stored last.
// Counted-wait safety: the only conditional ops younger than the Q-tile wait
// are the kv stores -> full blocks use WAITV(32) (32 stores younger than the
// 4 q-glls), boundary block drains WAITV(0). Uniform per block.
__global__ __launch_bounds__(512, 2) void k_qkv(
        const bf16* __restrict__ hb, const bf16* __restrict__ wqkvT,
        bf16* __restrict__ qb, bf16* __restrict__ kvb, int N) {
    __shared__ alignas(16) bf16 Wbuf[2][128 * 128];   // 64 KB -> 2 blocks/CU
    int m0 = blockIdx.x * BM;
    int t = threadIdx.x;
    int wave = t >> 6, lane = t & 63;
    int quad = lane >> 4, l16 = lane & 15;
    int wm = wave * 16;

    bf16x8 afr[4];
    load_afrag(hb, m0 + wm + l16, quad, N, afr);             // 4 vm (cond, oldest)
    FENCE();
    stage_full(Wbuf[0], wqkvT + (size_t)D * D, wave, lane);   // K tile (4 gll)
    FENCE();
    stage_full(Wbuf[1], wqkvT + (size_t)2 * D * D, wave, lane); // V tile (4 gll)
    FENCE();

    int rowb = m0 + wm + quad * 4;
    f32x4 ak[8], acc[8];
#pragma unroll
    for (int j = 0; j < 8; j++) ak[j] = (f32x4){0.f, 0.f, 0.f, 0.f};

    WAITV(4); BAR();                 // afr + K landed; V in flight
    __builtin_amdgcn_s_setprio(1);
    mfma_tile(Wbuf[0], afr, ak, l16, quad);
    __builtin_amdgcn_s_setprio(0);
    BAR();                           // buf0 free
    stage_full(Wbuf[0], wqkvT, wave, lane);   // Q tile (4 gll)
    FENCE();
#pragma unroll
    for (int j = 0; j < 8; j++) acc[j] = (f32x4){0.f, 0.f, 0.f, 0.f};
    WAITV(4); BAR();                 // V landed; Q in flight
    __builtin_amdgcn_s_setprio(1);
    mfma_tile(Wbuf[1], afr, acc, l16, quad);   // acc = V
    __builtin_amdgcn_s_setprio(0);

    // pack + store kv now (overlaps Q-tile gll latency)
#pragma unroll
    for (int j = 0; j < 8; j++) {
        int col = j * 16 + l16;
#pragma unroll
        for (int r = 0; r < 4; r++) {
            int gr = rowb + r;
            if (gr >= N) continue;
            uint kv = (uint)bfbits(ak[j][r]) | ((uint)bfbits(acc[j][r]) << 16);
            *(uint*)&kvb[((size_t)gr * D + col) * 2] = kv;
        }
    }
    FENCE();
    if (m0 + BM <= N) { WAITV(32); } else { WAITV(0); }   // Q tile landed
    BAR();
#pragma unroll
    for (int j = 0; j < 8; j++) acc[j] = (f32x4){0.f, 0.f, 0.f, 0.f};
    __builtin_amdgcn_s_setprio(1);
    mfma_tile(Wbuf[0], afr, acc, l16, quad);   // acc = Q
    __builtin_amdgcn_s_setprio(0);
#pragma unroll
    for (int j = 0; j < 8; j++) {
        int col = j * 16 + l16;
#pragma unroll
        for (int r = 0; r < 4; r++) {
            int gr = rowb + r;
            if (gr >= N) continue;
            qb[(size_t)gr * D + col] = __float2bfloat16(acc[j][r] * QSCALE_L2E);
        }
    }
}

// ---- stage FFN subtile ts (0..15): per c: {W1 h0, W1 h1, W2 h0, W2 h1} ----
__device__ __forceinline__ void stage_ffn_tile(int ts, const bf16* w1T,
                                               const bf16* w2T, bf16* Wb3,
                                               int wave, int lane) {
    int c = ts >> 2, ph = ts & 3;
    const bf16* src; int rs;
    if (ph < 2) { src = w1T + (size_t)(c * 128) * 128 + ph * 64; rs = 128; }
    else        { src = w2T + c * 128 + (ph - 2) * 64;           rs = DFF; }
    stage_half(Wb3 + (size_t)(ts % 3) * (64 * 128), src, rs, wave, lane);
}

// ---------------- fused FFN: 16-stage gll pipeline, ring of 3 subtiles ------
// x += relu(hb@w1+b1)@w2 + b2; then LN (MODE 0) or fused decode (MODE 1)
template<int MODE>
__global__ __launch_bounds__(512, 2) void k_ffn(
        const bf16* __restrict__ hb, const bf16* __restrict__ w1T,
        const float* __restrict__ b1,
        const bf16* __restrict__ w2T, const float* __restrict__ b2,
        const float* __restrict__ lns, const float* __restrict__ lnb,
        const float* __restrict__ dw1, const float* __restrict__ db1,
        const float* __restrict__ dw2, const float* __restrict__ db2,
        float* x, bf16* outB, float* out, int N) {
    __shared__ alignas(16) bf16 Wb3[3][64 * 128];   // 48 KB ring
    __shared__ alignas(16) bf16 Hsm[128 * 128];     // 32 KB (swizzled) => 80 KB
    int m0 = blockIdx.x * BM;
    int t = threadIdx.x;
    int wave = t >> 6, lane = t & 63;
    int quad = lane >> 4, l16 = lane & 15;
    int wm = wave * 16;
    int rowb = m0 + wm + quad * 4;

    // preload all b1 biases: keeps the pipeline free of stray vmem ops
    float b1pre[4][8];
#pragma unroll
    for (int c2 = 0; c2 < 4; c2++)
#pragma unroll
        for (int j = 0; j < 8; j++) b1pre[c2][j] = b1[c2 * 128 + j * 16 + l16];

    bf16x8 afr[4];
    load_afrag(hb, m0 + wm + l16, quad, N, afr);
    FENCE();
    stage_ffn_tile(0, w1T, w2T, &Wb3[0][0], wave, lane);
    FENCE();
    stage_ffn_tile(1, w1T, w2T, &Wb3[0][0], wave, lane);
    FENCE();

    f32x4 acc2[8], accP[8];
#pragma unroll
    for (int j = 0; j < 8; j++) acc2[j] = (f32x4){0.f, 0.f, 0.f, 0.f};
    float xv[8][4];

#pragma unroll
    for (int s = 0; s < 16; s++) {
        BAR();                       // all waves done reading tile s-1's slot
        if (s + 2 < 16) {
            stage_ffn_tile(s + 2, w1T, w2T, &Wb3[0][0], wave, lane);
            FENCE();
        }
        // tile s done (own parts); s+1, s+2 remain in flight (2 ops each)
        if (s < 14) { WAITV(4); } else if (s == 14) { WAITV(2); } else { WAITV(0); }
        BAR();                       // everyone's parts of tile s landed
        const bf16* Wb = &Wb3[0][0] + (size_t)(s % 3) * (64 * 128);
        int c = s >> 2, ph = s & 3;
        if (s == 15) {   // residual prefetch: hides under last stage + epilogue
#pragma unroll
            for (int j = 0; j < 8; j++)
#pragma unroll
                for (int r = 0; r < 4; r++) {
                    int gr = rowb + r;
                    xv[j][r] = (gr < N) ? x[(size_t)gr * D + j * 16 + l16] : 0.f;
                }
        }
        if (ph < 2) {
            if (ph == 0) {
#pragma unroll
                for (int j = 0; j < 8; j++) accP[j] = (f32x4){0.f, 0.f, 0.f, 0.f};
            }
            __builtin_amdgcn_s_setprio(1);
#pragma unroll
            for (int i2 = 0; i2 < 2; i2++) {
#pragma unroll
                for (int j = 0; j < 8; j++) {
                    const bf16* wp = Wb + (size_t)(j * 16 + l16) * 64
                                      + (size_t)(((i2 * 4 + quad) ^ (l16 & 7)) * 8);
                    accP[j] = __builtin_amdgcn_mfma_f32_16x16x32_bf16(
                        afr[ph * 2 + i2], *(const bf16x8*)wp, accP[j], 0, 0, 0);
                }
            }
            __builtin_amdgcn_s_setprio(0);
            if (ph == 1) {   // relu+bias -> swizzled Hsm (wave-private rows)
                int rw = wm + quad * 4;
#pragma unroll
                for (int j = 0; j < 8; j++) {
                    int gb = j * 2 + (l16 >> 3), ce = l16 & 7;
#pragma unroll
                    for (int r = 0; r < 4; r++) {
                        int row = rw + r;
                        Hsm[(size_t)row * 128 + (size_t)((gb ^ (row & 15)) * 8) + ce] =
                            __float2bfloat16(fmaxf(accP[j][r] + b1pre[c][j], 0.f));
                    }
                }
                WAITLGKM;   // own ds_writes drained before next-stage reads
            }
        } else {
            int h = ph - 2;
            __builtin_amdgcn_s_setprio(1);
#pragma unroll
            for (int k2 = 0; k2 < 2; k2++) {
                int ks = h * 2 + k2;
                const bf16* hp = Hsm + (size_t)(wm + l16) * 128
                                  + (size_t)(((ks * 4 + quad) ^ l16) * 8);
                bf16x8 af2 = *(const bf16x8*)hp;
#pragma unroll
                for (int j = 0; j < 8; j++) {
                    const bf16* wp = Wb + (size_t)(j * 16 + l16) * 64
                                      + (size_t)(((k2 * 4 + quad) ^ (l16 & 7)) * 8);
                    acc2[j] = __builtin_amdgcn_mfma_f32_16x16x32_bf16(
                        af2, *(const bf16x8*)wp, acc2[j], 0, 0, 0);
                }
            }
            __builtin_amdgcn_s_setprio(0);
        }
    }

    float bv[8];
#pragma unroll
    for (int j = 0; j < 8; j++) bv[j] = b2[j * 16 + l16];
#pragma unroll
    for (int j = 0; j < 8; j++) {
#pragma unroll
        for (int r = 0; r < 4; r++) {
            int gr = rowb + r;
            if (gr >= N) continue;
            acc2[j][r] += bv[j] + xv[j][r];
        }
    }
    if (MODE == 1) {
        float dw[8][3];
#pragma unroll
        for (int j = 0; j < 8; j++) {
            int col = j * 16 + l16;
#pragma unroll
            for (int cc3 = 0; cc3 < 3; cc3++) dw[j][cc3] = dw1[col * 3 + cc3];
        }
#pragma unroll
        for (int r = 0; r < 4; r++) {
            float s0 = 0.f, s1 = 0.f, s2 = 0.f;
#pragma unroll
            for (int j = 0; j < 8; j++) {
                float v = acc2[j][r];
                s0 += v * dw[j][0]; s1 += v * dw[j][1]; s2 += v * dw[j][2];
            }
            s0 += __shfl_xor(s0, 1, 64); s1 += __shfl_xor(s1, 1, 64); s2 += __shfl_xor(s2, 1, 64);
            s0 += __shfl_xor(s0, 2, 64); s1 += __shfl_xor(s1, 2, 64); s2 += __shfl_xor(s2, 2, 64);
            s0 += __shfl_xor(s0, 4, 64); s1 += __shfl_xor(s1, 4, 64); s2 += __shfl_xor(s2, 4, 64);
            s0 += __shfl_xor(s0, 8, 64); s1 += __shfl_xor(s1, 8, 64); s2 += __shfl_xor(s2, 8, 64);
            int gr = rowb + r;
            if (l16 == 0 && gr < N) {
                float t0 = fmaxf(s0 + db1[0], 0.f);
                float t1 = fmaxf(s1 + db1[1], 0.f);
                float t2 = fmaxf(s2 + db1[2], 0.f);
#pragma unroll
                for (int o = 0; o < 3; o++)
                    out[(size_t)gr * 3 + o] =
                        t0 * dw2[0 * 3 + o] + t1 * dw2[1 * 3 + o] + t2 * dw2[2 * 3 + o] + db2[o];
            }
        }
        return;
    }
    float lsv[8], lbv[8];
#pragma unroll
    for (int j = 0; j < 8; j++) {
        lsv[j] = lns[j * 16 + l16];
        lbv[j] = lnb[j * 16 + l16];
    }
#pragma unroll
    for (int r = 0; r < 4; r++) {
        float s1 = 0.f, s2 = 0.f;
#pragma unroll
        for (int j = 0; j < 8; j++) {
            float v = acc2[j][r];
            s1 += v; s2 += v * v;
        }
        s1 += __shfl_xor(s1, 1, 64);  s2 += __shfl_xor(s2, 1, 64);
        s1 += __shfl_xor(s1, 2, 64);  s2 += __shfl_xor(s2, 2, 64);
        s1 += __shfl_xor(s1, 4, 64);  s2 += __shfl_xor(s2, 4, 64);
        s1 += __shfl_xor(s1, 8, 64);  s2 += __shfl_xor(s2, 8, 64);
        float mu = s1 * (1.f / 128.f);
        float var = s2 * (1.f / 128.f) - mu * mu;
        float rinv = rsqrtf(fmaxf(var, 0.f) + 1e-5f);
        int gr = rowb + r;
        if (gr >= N) continue;
#pragma unroll
        for (int j = 0; j < 8; j++) {
            int col = j * 16 + l16;
            float v = acc2[j][r];
            x[(size_t)gr * D + col] = v;
            outB[(size_t)gr * D + col] = __float2bfloat16((v - mu) * rinv * lsv[j] + lbv[j]);
        }
    }
}

// ---------------- encoder stage 1: hb = bf16(relu(f@w1+b1)) ----------------
__global__ void k_enc1(const float* __restrict__ feat,
                       const float* __restrict__ w1, const float* __restrict__ b1,
                       bf16* __restrict__ hb, int N) {
    __shared__ float fsh[TN][DIN];
    int n0 = blockIdx.x * TN;
    int j = threadIdx.x;            // 0..127
    int nvalid = min(TN, N - n0);
    for (int idx = j; idx < TN * DIN; idx += 128) {
        int n = idx / DIN, i = idx % DIN;
        fsh[n][i] = (n < nvalid) ? feat[(n0 + n) * DIN + i] : 0.f;
    }
    __syncthreads();
    float bb = b1[j];
#pragma unroll
    for (int n = 0; n < TN; n++) {
        float a = bb;
#pragma unroll
        for (int i = 0; i < DIN; i++) a += fsh[n][i] * w1[i * D + j];
        if (n < nvalid) hb[(size_t)(n0 + n) * D + j] = __float2bfloat16(fmaxf(a, 0.f));
    }
}

// ---------------- attention: one wave per receiver, 16-edge window ----------
// Direct per-edge index loads (r19's shfl broadcast regressed); 2 slots x
// 8-deep = 16 edges in flight; 90% of waves (deg<=16) need one gather round.
__device__ __forceinline__ void attn_edge(uint4 w, bool v, float4 qv,
                                          float& l, float& a0, float& a1,
                                          float& a2, float& a3) {
    float k0 = __uint_as_float(w.x << 16), v0 = __uint_as_float(w.x & 0xFFFF0000u);
    float k1 = __uint_as_float(w.y << 16), v1 = __uint_as_float(w.y & 0xFFFF0000u);
    float k2 = __uint_as_float(w.z << 16), v2 = __uint_as_float(w.z & 0xFFFF0000u);
    float k3 = __uint_as_float(w.w << 16), v3 = __uint_as_float(w.w & 0xFFFF0000u);
    float p = qv.x * k0 + qv.y * k1 + qv.z * k2 + qv.w * k3;
    p += __shfl_xor(p, 1, 64);
    p += __shfl_xor(p, 2, 64);
    p += __shfl_xor(p, 4, 64);
    float e = v ? exp2f(p) : 0.f;
    l += e;
    a0 += e * v0; a1 += e * v1; a2 += e * v2; a3 += e * v3;
}

__global__ __launch_bounds__(256) void k_attn(
        const bf16* __restrict__ qb, const uint* __restrict__ kvb,
        const int* __restrict__ deg, const int* __restrict__ eid,
        bf16* __restrict__ out, int N) {
    int wave = threadIdx.x >> 6, lane = threadIdx.x & 63;
    int r = blockIdx.x * 4 + wave;
    if (r >= N) return;
    int g = lane & 7;                    // dim group
    int h = (lane >> 3) & 3;             // head
    int slot = lane >> 5;                // edge slot 0..1
    int d0 = h * 32 + g * 4;
    uint2 qw = *(const uint2*)(qb + (size_t)r * D + d0);
    float4 qv;
    qv.x = __uint_as_float(qw.x << 16);
    qv.y = __uint_as_float(qw.x & 0xFFFF0000u);
    qv.z = __uint_as_float(qw.y << 16);
    qv.w = __uint_as_float(qw.y & 0xFFFF0000u);
    int cnt = min(deg[r], MAXDEG);
    const int* row = eid + (size_t)r * MAXDEG;
    const uint* kvbase = kvb + d0;
    float l = 0.f, a0 = 0.f, a1 = 0.f, a2 = 0.f, a3 = 0.f;
    for (int base = 0; base < cnt; base += 16) {
        int ss[8];
        bool vv[8];
#pragma unroll
        for (int u = 0; u < 8; u++) {
            int e = base + u * 2 + slot;
            vv[u] = e < cnt;
            ss[u] = vv[u] ? row[e] : 0;
        }
        uint4 w[8];
#pragma unroll
        for (int u = 0; u < 8; u++)
            w[u] = *(const uint4*)(kvbase + (size_t)ss[u] * D);
#pragma unroll
        for (int u = 0; u < 8; u++)
            attn_edge(w[u], vv[u], qv, l, a0, a1, a2, a3);
    }
    // combine the 2 edge slots (lane bit 5)
    l  += __shfl_xor(l, 32, 64);
    a0 += __shfl_xor(a0, 32, 64);
    a1 += __shfl_xor(a1, 32, 64);
    a2 += __shfl_xor(a2, 32, 64);
    a3 += __shfl_xor(a3, 32, 64);
    if (lane < 32) {
        float inv = 1.f / (l + 1e-9f);
        bf16 o[4];
        o[0] = __float2bfloat16(a0 * inv);
        o[1] = __float2bfloat16(a1 * inv);
        o[2] = __float2bfloat16(a2 * inv);
        o[3] = __float2bfloat16(a3 * inv);
        *(uint2*)(out + (size_t)r * D + d0) = *(uint2*)o;
    }
}

extern "C" void kernel_launch(void* const* d_in, const int* in_sizes, int n_in,
                              void* d_out, int out_size, void* d_ws, size_t ws_size,
                              hipStream_t stream) {
    const float* feat    = (const float*)d_in[0];
    const int*   senders = (const int*)d_in[1];
    const int*   recv    = (const int*)d_in[2];
    const float* enc_w1  = (const float*)d_in[3];
    const float* enc_b1  = (const float*)d_in[4];
    const float* enc_w2  = (const float*)d_in[5];
    const float* enc_b2  = (const float*)d_in[6];
    const float* wq      = (const float*)d_in[7];
    const float* wk      = (const float*)d_in[8];
    const float* wv      = (const float*)d_in[9];
    const float* wo      = (const float*)d_in[10];
    const float* ln1_s   = (const float*)d_in[11];
    const float* ln1_b   = (const float*)d_in[12];
    const float* ffn_w1  = (const float*)d_in[13];
    const float* ffn_b1  = (const float*)d_in[14];
    const float* ffn_w2  = (const float*)d_in[15];
    const float* ffn_b2  = (const float*)d_in[16];
    const float* ln2_s   = (const float*)d_in[17];
    const float* ln2_b   = (const float*)d_in[18];
    const float* dec_w1  = (const float*)d_in[19];
    const float* dec_b1  = (const float*)d_in[20];
    const float* dec_w2  = (const float*)d_in[21];
    const float* dec_b2  = (const float*)d_in[22];

    int N = in_sizes[0] / DIN;
    int E = in_sizes[1];

    // workspace layout
    char* p = (char*)d_ws;
    float* x   = (float*)p;  p += (size_t)N * D * 4;        // residual fp32
    bf16*  qb  = (bf16*)p;   p += (size_t)N * D * 2;        // q bf16 (pre-scaled)
    bf16*  kvb = (bf16*)p;   p += (size_t)N * D * 2 * 2;    // (k,v) bf16 interleaved
    bf16*  hb  = (bf16*)p;   p += (size_t)N * D * 2;        // LN out / attn out bf16
    int* deg   = (int*)p;    p += (size_t)N * 4;
    int* eid   = (int*)p;    p += (size_t)N * MAXDEG * 4;
    bf16* wqkvT  = (bf16*)p; p += (size_t)4 * 3 * D * D * 2;
    bf16* woT    = (bf16*)p; p += (size_t)4 * D * D * 2;
    bf16* w1T    = (bf16*)p; p += (size_t)4 * D * DFF * 2;
    bf16* w2T    = (bf16*)p; p += (size_t)4 * DFF * D * 2;
    bf16* encw2T = (bf16*)p; p += (size_t)D * D * 2;

    int gm = (N + BM - 1) / BM;   // 391

    k_wt<<<dim3(256, 26), 256, 0, stream>>>(wq, wk, wv, wo, ffn_w1, ffn_w2, enc_w2,
                                            wqkvT, woT, w1T, w2T, encw2T, deg, N);
    k_fill<<<(E + 255) / 256, 256, 0, stream>>>(recv, senders, deg, eid, E);
    k_enc1<<<(N + TN - 1) / TN, 128, 0, stream>>>(feat, enc_w1, enc_b1, hb, N);
    // x = hb @ enc_w2 + b2; hb = LN1_0(x)
    k_gemm<5><<<gm, 512, 0, stream>>>(hb, encw2T, enc_b2, ln1_s, ln1_b, x, hb, N);

    for (int l = 0; l < 4; l++) {
        k_qkv<<<gm, 512, 0, stream>>>(hb, wqkvT + (size_t)l * 3 * D * D, qb, kvb, N);
        k_attn<<<(N + 3) / 4, 256, 0, stream>>>(qb, (const uint*)kvb, deg, eid, hb, N);
        // x += hb @ wo; hb = LN2(x)
        k_gemm<2><<<gm, 512, 0, stream>>>(hb, woT + (size_t)l * D * D,
                                          nullptr, ln2_s + l * D, ln2_b + l * D,
                                          x, hb, N);
        // x += relu(hb@w1+b1)@w2 + b2; then LN1_{l+1} (l<3) or fused decode (l=3)
        if (l < 3)
            k_ffn<0><<<gm, 512, 0, stream>>>(hb, w1T + (size_t)l * D * DFF,
                                             ffn_b1 + l * DFF,
                                             w2T + (size_t)l * DFF * D, ffn_b2 + l * D,
                                             ln1_s + (l + 1) * D, ln1_b + (l + 1) * D,
                                             nullptr, nullptr, nullptr, nullptr,
                                             x, hb, nullptr, N);
        else
            k_ffn<1><<<gm, 512, 0, stream>>>(hb, w1T + (size_t)l * D * DFF,
                                             ffn_b1 + l * DFF,
                                             w2T + (size_t)l * DFF * D, ffn_b2 + l * D,
                                             nullptr, nullptr,
                                             dec_w1, dec_b1, dec_w2, dec_b2,
                                             x, nullptr, (float*)d_out, N);
    }
}